// Round 4
// baseline (671.874 us; speedup 1.0000x reference)
//
#include <hip/hip_runtime.h>

// QORNN: quantized orthogonal RNN — exact-integer recurrence.
// v7: batch-2 ILP. Evidence r1-r3: per-row VALU issue ~500cy/step is fixed
// (sdot ~4cy/wave64); ~400cy/step of latency (post-barrier ds_read + reduce +
// modrelu tail) is unhideable by TLP (v5 null: waves barrier-phase-locked) and
// MFMA broadcast wastes 15/16 of the pipe (v6: +28% dur). Remaining resource:
// independent batch rows. Grid 128; each block runs TWO rows; each wave does
// v3's per-wave work for BOTH rows, sharing Wr/Wi register fragments. The two
// rows' chains are independent -> row B's sdots fill row A's stalls (in-wave
// ILP, no extra barrier skew). LDS: weights staged via xlds scratch, then
// 2x64KB x rows + Wo + h ~= 136KB. Arithmetic v3-verbatim.

#define TSEQ 1024
#define IDIM 64
#define HDIM 256
#define ODIM 16
#define XROW (TSEQ * 16 + 16)   // dwords per staged x row (64KB + pad)

__device__ __forceinline__ int sdot4i8(int a, int b, int c) {
#if __has_builtin(__builtin_amdgcn_sdot4)
    return __builtin_amdgcn_sdot4(a, b, c, false);
#else
    int r = c;
    r += ((a << 24) >> 24) * ((b << 24) >> 24);
    r += ((a << 16) >> 24) * ((b << 16) >> 24);
    r += ((a << 8)  >> 24) * ((b << 8)  >> 24);
    r += (a >> 24) * (b >> 24);
    return r;
#endif
}

__device__ __forceinline__ int qpack4(float4 f, float s, float lo, float hi) {
    int a = (int)fminf(fmaxf(rintf(f.x * s), lo), hi);
    int b = (int)fminf(fmaxf(rintf(f.y * s), lo), hi);
    int c = (int)fminf(fmaxf(rintf(f.z * s), lo), hi);
    int d = (int)fminf(fmaxf(rintf(f.w * s), lo), hi);
    return (a & 255) | ((b & 255) << 8) | ((c & 255) << 16) | ((d & 255) << 24);
}

// quad butterfly sum: all 4 lanes of each quad end with the quad-sum
__device__ __forceinline__ int qsum(int v) {
    v += __builtin_amdgcn_update_dpp(0, v, 0xB1, 0xF, 0xF, true); // quad_perm xor1
    v += __builtin_amdgcn_update_dpp(0, v, 0x4E, 0xF, 0xF, true); // quad_perm xor2
    return v;
}

__global__ __launch_bounds__(256, 1)
void qornn_kernel(const float* __restrict__ x, const float* __restrict__ Wi,
                  const float* __restrict__ Wr, const float* __restrict__ Wo,
                  const float* __restrict__ bias, float* __restrict__ out) {
    __shared__ alignas(16) int xlds[2][XROW];   // 2 x-rows, int8-packed (~128KB)
    __shared__ alignas(16) int wolds[1024];     // Wo int8, 4KB, resident
    __shared__ alignas(16) int hbuf[2][2][64];  // [buf][row][o/4] (256 int8 per row)

    const int tid  = threadIdx.x;
    const int brow = blockIdx.x;                // row pair: rows 2*brow, 2*brow+1
    const int w    = tid >> 6;                  // wave 0..3
    const int l    = tid & 63;
    const int q    = l & 3;                     // k-quarter; also output slot in quad
    const int m16  = l >> 2;                    // quad id in wave
    const int obase = w * 64 + m16 * 4;         // outputs obase..obase+3 (obase+q == tid)

    int* wstage = &xlds[0][0];                  // 32KB weight-staging scratch (pre-x)

    // ---- stage Wi [256 x 64] fp32 -> int8 (scale 8); lane keeps 4 quarter-rows ----
    {
        const float4* wi4 = (const float4*)Wi;
        #pragma unroll
        for (int it = 0; it < 16; ++it) {
            int flat = it * 256 + tid;
            wstage[flat] = qpack4(wi4[flat], 8.0f, -8.0f, 7.0f);
        }
    }
    __syncthreads();
    int4 wiq[4];   // wiq[i] = Wi[obase+i][q*16 .. q*16+15]
    {
        const int4* p = (const int4*)wstage;
        #pragma unroll
        for (int i = 0; i < 4; ++i) wiq[i] = p[(obase + i) * 4 + q];
    }
    __syncthreads();

    // ---- stage Wr [256 x 256] -> int8 in two halves; lane keeps 4 quarter-rows ----
    int4 wr[16];   // wr[i*4+r] = Wr[obase+i][q*64 + r*16 .. +15]
    {
        const float4* wr4 = (const float4*)Wr;
        #pragma unroll
        for (int it = 0; it < 32; ++it) {
            int flat = it * 256 + tid;
            wstage[flat] = qpack4(wr4[flat], 8.0f, -8.0f, 7.0f);
        }
        __syncthreads();
        if (obase < 128) {
            const int4* p = (const int4*)wstage;
            #pragma unroll
            for (int i = 0; i < 4; ++i)
                #pragma unroll
                for (int r = 0; r < 4; ++r)
                    wr[i * 4 + r] = p[(obase + i) * 16 + q * 4 + r];
        }
        __syncthreads();
        #pragma unroll
        for (int it = 0; it < 32; ++it) {
            int flat = it * 256 + tid;
            wstage[flat] = qpack4(wr4[8192 + flat], 8.0f, -8.0f, 7.0f);
        }
        __syncthreads();
        if (obase >= 128) {
            const int4* p = (const int4*)wstage;
            #pragma unroll
            for (int i = 0; i < 4; ++i)
                #pragma unroll
                for (int r = 0; r < 4; ++r)
                    wr[i * 4 + r] = p[(obase - 128 + i) * 16 + q * 4 + r];
        }
        __syncthreads();
    }

    // ---- stage Wo [16 x 256] -> int8 into wolds (resident; epilogue only) ----
    {
        const float4* wo4 = (const float4*)Wo;
        #pragma unroll
        for (int it = 0; it < 4; ++it) {
            int flat = it * 256 + tid;
            wolds[flat] = qpack4(wo4[flat], 8.0f, -8.0f, 7.0f);
        }
    }

    // ---- stage both x rows to LDS as int8 (scale 128); overwrites wstage ----
    {
        #pragma unroll
        for (int r = 0; r < 2; ++r) {
            const float4* rowf4 =
                (const float4*)(x + (size_t)(2 * brow + r) * (TSEQ * IDIM));
            #pragma unroll 8
            for (int it = 0; it < 64; ++it) {
                int flat = it * 256 + tid;           // float4 idx == packed dword idx
                xlds[r][flat] = qpack4(rowf4[flat], 128.0f, -128.0f, 127.0f);
            }
        }
    }
    if (tid < 128) ((int*)hbuf[0])[tid] = 0;         // h0 = 0 for both rows
    __syncthreads();

    const float bv = bias[tid];                      // bias for output tid (== obase+q)
    const bool qb0 = (q & 1) != 0;
    const bool qb1 = (q & 2) != 0;

    // u accumulators for t=0, both rows
    int uA[4], uB[4];
    {
        const int4 xxA = ((const int4*)xlds[0])[q];
        const int4 xxB = ((const int4*)xlds[1])[q];
        #pragma unroll
        for (int i = 0; i < 4; ++i) {
            int s = sdot4i8(xxA.x, wiq[i].x, 0);
            s = sdot4i8(xxA.y, wiq[i].y, s);
            s = sdot4i8(xxA.z, wiq[i].z, s);
            uA[i] = sdot4i8(xxA.w, wiq[i].w, s);
            int p = sdot4i8(xxB.x, wiq[i].x, 0);
            p = sdot4i8(xxB.y, wiq[i].y, p);
            p = sdot4i8(xxB.z, wiq[i].z, p);
            uB[i] = sdot4i8(xxB.w, wiq[i].w, p);
        }
    }

    // ---- main recurrence: 1024 steps, 2 independent rows per step, 1 barrier ----
    #pragma unroll 2
    for (int t = 0; t < TSEQ; ++t) {
        // issue all LDS reads first: both rows' h quarters + next-x quarters
        int4 hhA[4], hhB[4];
        {
            const int4* hPA = (const int4*)hbuf[t & 1][0];
            const int4* hPB = (const int4*)hbuf[t & 1][1];
            #pragma unroll
            for (int r = 0; r < 4; ++r) hhA[r] = hPA[q * 4 + r];
            #pragma unroll
            for (int r = 0; r < 4; ++r) hhB[r] = hPB[q * 4 + r];
        }
        const int4 xnA = ((const int4*)xlds[0])[(t + 1) * 4 + q];
        const int4 xnB = ((const int4*)xlds[1])[(t + 1) * 4 + q];

        // row A z partials (two 8-deep chains per output, seeded with uA[i])
        int zaA[4], zbA[4], zaB[4], zbB[4];
        #pragma unroll
        for (int i = 0; i < 4; ++i) {
            int s0 = uA[i];
            s0 = sdot4i8(hhA[0].x, wr[i * 4 + 0].x, s0);
            s0 = sdot4i8(hhA[0].y, wr[i * 4 + 0].y, s0);
            s0 = sdot4i8(hhA[0].z, wr[i * 4 + 0].z, s0);
            s0 = sdot4i8(hhA[0].w, wr[i * 4 + 0].w, s0);
            s0 = sdot4i8(hhA[1].x, wr[i * 4 + 1].x, s0);
            s0 = sdot4i8(hhA[1].y, wr[i * 4 + 1].y, s0);
            s0 = sdot4i8(hhA[1].z, wr[i * 4 + 1].z, s0);
            s0 = sdot4i8(hhA[1].w, wr[i * 4 + 1].w, s0);
            int s1 = 0;
            s1 = sdot4i8(hhA[2].x, wr[i * 4 + 2].x, s1);
            s1 = sdot4i8(hhA[2].y, wr[i * 4 + 2].y, s1);
            s1 = sdot4i8(hhA[2].z, wr[i * 4 + 2].z, s1);
            s1 = sdot4i8(hhA[2].w, wr[i * 4 + 2].w, s1);
            s1 = sdot4i8(hhA[3].x, wr[i * 4 + 3].x, s1);
            s1 = sdot4i8(hhA[3].y, wr[i * 4 + 3].y, s1);
            s1 = sdot4i8(hhA[3].z, wr[i * 4 + 3].z, s1);
            s1 = sdot4i8(hhA[3].w, wr[i * 4 + 3].w, s1);
            zaA[i] = s0; zbA[i] = s1;
        }
        // row B z partials (independent chains -> fill row A's stalls)
        #pragma unroll
        for (int i = 0; i < 4; ++i) {
            int s0 = uB[i];
            s0 = sdot4i8(hhB[0].x, wr[i * 4 + 0].x, s0);
            s0 = sdot4i8(hhB[0].y, wr[i * 4 + 0].y, s0);
            s0 = sdot4i8(hhB[0].z, wr[i * 4 + 0].z, s0);
            s0 = sdot4i8(hhB[0].w, wr[i * 4 + 0].w, s0);
            s0 = sdot4i8(hhB[1].x, wr[i * 4 + 1].x, s0);
            s0 = sdot4i8(hhB[1].y, wr[i * 4 + 1].y, s0);
            s0 = sdot4i8(hhB[1].z, wr[i * 4 + 1].z, s0);
            s0 = sdot4i8(hhB[1].w, wr[i * 4 + 1].w, s0);
            int s1 = 0;
            s1 = sdot4i8(hhB[2].x, wr[i * 4 + 2].x, s1);
            s1 = sdot4i8(hhB[2].y, wr[i * 4 + 2].y, s1);
            s1 = sdot4i8(hhB[2].z, wr[i * 4 + 2].z, s1);
            s1 = sdot4i8(hhB[2].w, wr[i * 4 + 2].w, s1);
            s1 = sdot4i8(hhB[3].x, wr[i * 4 + 3].x, s1);
            s1 = sdot4i8(hhB[3].y, wr[i * 4 + 3].y, s1);
            s1 = sdot4i8(hhB[3].z, wr[i * 4 + 3].z, s1);
            s1 = sdot4i8(hhB[3].w, wr[i * 4 + 3].w, s1);
            zaB[i] = s0; zbB[i] = s1;
        }

        // u for step t+1, both rows (h-independent filler)
        int unA[4], unB[4];
        #pragma unroll
        for (int i = 0; i < 4; ++i) {
            int s = sdot4i8(xnA.x, wiq[i].x, 0);
            s = sdot4i8(xnA.y, wiq[i].y, s);
            s = sdot4i8(xnA.z, wiq[i].z, s);
            unA[i] = sdot4i8(xnA.w, wiq[i].w, s);
            int p = sdot4i8(xnB.x, wiq[i].x, 0);
            p = sdot4i8(xnB.y, wiq[i].y, p);
            p = sdot4i8(xnB.z, wiq[i].z, p);
            unB[i] = sdot4i8(xnB.w, wiq[i].w, p);
        }

        // quad-reduce; lane keeps output obase+q of each row
        const int z0A = qsum(zaA[0] + zbA[0]);
        const int z1A = qsum(zaA[1] + zbA[1]);
        const int z2A = qsum(zaA[2] + zbA[2]);
        const int z3A = qsum(zaA[3] + zbA[3]);
        const int z0B = qsum(zaB[0] + zbB[0]);
        const int z1B = qsum(zaB[1] + zbB[1]);
        const int z2B = qsum(zaB[2] + zbB[2]);
        const int z3B = qsum(zaB[3] + zbB[3]);
        const int zloA = qb0 ? z1A : z0A;
        const int zhiA = qb0 ? z3A : z2A;
        const int zA   = qb1 ? zhiA : zloA;
        const int zloB = qb0 ? z1B : z0B;
        const int zhiB = qb0 ? z3B : z2B;
        const int zB   = qb1 ? zhiB : zloB;

        // exact modrelu + 8-bit requantize (v3 arithmetic, verbatim) — row A
        {
            const float zf = (float)zA;
            const float t1 = fmaf(fabsf(zf), 0.0009765625f, bv);
            const float t2 = fmaxf(t1, 0.0f);
            const float r  = rintf(t2 * 128.0f);
            const int vpos = (int)fminf(r, 127.0f);
            const int vneg = -(int)fminf(r, 128.0f);
            int hv = (zA < 0) ? vneg : vpos;
            hv = (zA == 0) ? 0 : hv;
            ((signed char*)hbuf[(t + 1) & 1][0])[tid] = (signed char)hv;
        }
        // row B
        {
            const float zf = (float)zB;
            const float t1 = fmaf(fabsf(zf), 0.0009765625f, bv);
            const float t2 = fmaxf(t1, 0.0f);
            const float r  = rintf(t2 * 128.0f);
            const int vpos = (int)fminf(r, 127.0f);
            const int vneg = -(int)fminf(r, 128.0f);
            int hv = (zB < 0) ? vneg : vpos;
            hv = (zB == 0) ? 0 : hv;
            ((signed char*)hbuf[(t + 1) & 1][1])[tid] = (signed char)hv;
        }

        #pragma unroll
        for (int i = 0; i < 4; ++i) { uA[i] = unA[i]; uB[i] = unB[i]; }
        __syncthreads();
    }

    // ---- epilogue: out[2*brow+r, o] = h_last(r) . Wo_row(o) / 1024 ----
    if (tid < 2 * ODIM) {
        const int r = tid >> 4;
        const int o = tid & 15;
        const int4* wo = (const int4*)wolds;
        const int4* hl = (const int4*)hbuf[0][r];    // t=1024 even -> buf 0
        int a0 = 0, a1 = 0, a2 = 0, a3 = 0;
        #pragma unroll
        for (int i = 0; i < 16; ++i) {
            int4 w4 = wo[o * 16 + i];
            int4 h4 = hl[i];
            a0 = sdot4i8(h4.x, w4.x, a0);
            a1 = sdot4i8(h4.y, w4.y, a1);
            a2 = sdot4i8(h4.z, w4.z, a2);
            a3 = sdot4i8(h4.w, w4.w, a3);
        }
        out[(2 * brow + r) * ODIM + o] = (float)((a0 + a1) + (a2 + a3)) * 0.0009765625f;
    }
}

extern "C" void kernel_launch(void* const* d_in, const int* in_sizes, int n_in,
                              void* d_out, int out_size, void* d_ws, size_t ws_size,
                              hipStream_t stream) {
    const float* x  = (const float*)d_in[0];   // [B, T, I]
    const float* Wi = (const float*)d_in[1];   // [H, I]
    const float* Wr = (const float*)d_in[2];   // [H, H]
    const float* Wo = (const float*)d_in[3];   // [O, H]
    const float* b  = (const float*)d_in[4];   // [H]
    float* out = (float*)d_out;                // [B, O]

    const int B = in_sizes[0] / (TSEQ * IDIM); // 256
    qornn_kernel<<<B / 2, HDIM, 0, stream>>>(x, Wi, Wr, Wo, b, out);
}

// Round 5
// 441.470 us; speedup vs baseline: 1.5219x; 1.5219x over previous
//
#include <hip/hip_runtime.h>

// QORNN: quantized orthogonal RNN — exact-integer recurrence.
// v8: v3 base (372us, passing) + two latency-targeted edits. Evidence r0-r4:
//  - issue floor ~500cy/step (v_dot4 ~4.1cy/wave64, confirmed via v7 active-CU
//    VALUBusy); exposed serial ~370cy; full chip forces 1 row/block (v7: batch-2
//    halves the grid, net loss); TLP null (v5); MFMA broadcast loss (v6).
// Edits vs v3 (arithmetic/modrelu/reduce VERBATIM):
//  1. distance-2 x prefetch: xc register carries x_{t+1} across the barrier,
//     so the 16 u-sdots have NO same-step LDS dependency and fill the
//     post-barrier ds_read-h bubble (~120cy). v3's un depended on a same-step
//     ds_read xn and sat inside the bubble.
//  2. 4-way z-chain split (za/zb/zc/zd, 4-deep): post-h chain-through 64->32cy
//     at +8 adds. If this round fails correctness, edit 1 (schedule) is the
//     identified culprit (v4 post-mortem), and chain-split runs alone next.

#define TSEQ 1024
#define IDIM 64
#define HDIM 256
#define ODIM 16

__device__ __forceinline__ int sdot4i8(int a, int b, int c) {
#if __has_builtin(__builtin_amdgcn_sdot4)
    return __builtin_amdgcn_sdot4(a, b, c, false);
#else
    int r = c;
    r += ((a << 24) >> 24) * ((b << 24) >> 24);
    r += ((a << 16) >> 24) * ((b << 16) >> 24);
    r += ((a << 8)  >> 24) * ((b << 8)  >> 24);
    r += (a >> 24) * (b >> 24);
    return r;
#endif
}

__device__ __forceinline__ int qpack4(float4 f, float s, float lo, float hi) {
    int a = (int)fminf(fmaxf(rintf(f.x * s), lo), hi);
    int b = (int)fminf(fmaxf(rintf(f.y * s), lo), hi);
    int c = (int)fminf(fmaxf(rintf(f.z * s), lo), hi);
    int d = (int)fminf(fmaxf(rintf(f.w * s), lo), hi);
    return (a & 255) | ((b & 255) << 8) | ((c & 255) << 16) | ((d & 255) << 24);
}

// quad butterfly sum: all 4 lanes of each quad end with the quad-sum
__device__ __forceinline__ int qsum(int v) {
    v += __builtin_amdgcn_update_dpp(0, v, 0xB1, 0xF, 0xF, true); // quad_perm xor1
    v += __builtin_amdgcn_update_dpp(0, v, 0x4E, 0xF, 0xF, true); // quad_perm xor2
    return v;
}

__global__ __launch_bounds__(256, 1)
void qornn_kernel(const float* __restrict__ x, const float* __restrict__ Wi,
                  const float* __restrict__ Wr, const float* __restrict__ Wo,
                  const float* __restrict__ bias, float* __restrict__ out) {
    __shared__ alignas(16) int xlds[TSEQ * 16 + 48]; // whole row, int8-packed (64KB + pad)
    __shared__ alignas(16) int wstage[8192];         // 32 KB staging; Wo resident after init
    __shared__ alignas(16) int hbuf[2][64];          // double-buffered h (256 int8 each)

    const int tid = threadIdx.x;
    const int brow = blockIdx.x;
    const int w    = tid >> 6;          // wave 0..3
    const int l    = tid & 63;
    const int q    = l & 3;             // k-quarter this lane reads; also its output slot
    const int m16  = l >> 2;            // quad id in wave
    const int obase = w * 64 + m16 * 4; // outputs obase..obase+3 (obase+q == tid)

    // ---- stage Wi [256 x 64] fp32 -> int8 (scale 8); lane keeps 4 quarter-rows ----
    {
        const float4* wi4 = (const float4*)Wi;
        #pragma unroll
        for (int it = 0; it < 16; ++it) {
            int flat = it * 256 + tid;
            wstage[flat] = qpack4(wi4[flat], 8.0f, -8.0f, 7.0f);
        }
    }
    __syncthreads();
    int4 wiq[4];   // wiq[i] = Wi[obase+i][q*16 .. q*16+15]
    {
        const int4* p = (const int4*)wstage;
        #pragma unroll
        for (int i = 0; i < 4; ++i) wiq[i] = p[(obase + i) * 4 + q];
    }
    __syncthreads();

    // ---- stage Wr [256 x 256] -> int8 in two halves; lane keeps 4 quarter-rows ----
    int4 wr[16];   // wr[i*4+r] = Wr[obase+i][q*64 + r*16 .. +15]
    {
        const float4* wr4 = (const float4*)Wr;
        #pragma unroll
        for (int it = 0; it < 32; ++it) {
            int flat = it * 256 + tid;
            wstage[flat] = qpack4(wr4[flat], 8.0f, -8.0f, 7.0f);
        }
        __syncthreads();
        if (obase < 128) {
            const int4* p = (const int4*)wstage;
            #pragma unroll
            for (int i = 0; i < 4; ++i)
                #pragma unroll
                for (int r = 0; r < 4; ++r)
                    wr[i * 4 + r] = p[(obase + i) * 16 + q * 4 + r];
        }
        __syncthreads();
        #pragma unroll
        for (int it = 0; it < 32; ++it) {
            int flat = it * 256 + tid;
            wstage[flat] = qpack4(wr4[8192 + flat], 8.0f, -8.0f, 7.0f);
        }
        __syncthreads();
        if (obase >= 128) {
            const int4* p = (const int4*)wstage;
            #pragma unroll
            for (int i = 0; i < 4; ++i)
                #pragma unroll
                for (int r = 0; r < 4; ++r)
                    wr[i * 4 + r] = p[(obase - 128 + i) * 16 + q * 4 + r];
        }
        __syncthreads();
    }

    // ---- stage Wo [16 x 256] -> int8, resident in wstage[0..1023] ----
    {
        const float4* wo4 = (const float4*)Wo;
        #pragma unroll
        for (int it = 0; it < 4; ++it) {
            int flat = it * 256 + tid;
            wstage[flat] = qpack4(wo4[flat], 8.0f, -8.0f, 7.0f);
        }
    }

    // ---- stage entire x row to LDS as int8 (scale 128) ----
    {
        const float4* rowf4 = (const float4*)(x + (size_t)brow * (TSEQ * IDIM));
        #pragma unroll 8
        for (int it = 0; it < 64; ++it) {
            int flat = it * 256 + tid;               // float4 idx == packed dword idx
            xlds[flat] = qpack4(rowf4[flat], 128.0f, -128.0f, 127.0f);
        }
    }
    if (tid < 64) hbuf[0][tid] = 0;                  // h0 = 0
    __syncthreads();

    const float bv = bias[tid];                      // bias for output tid (== obase+q)
    const bool qb0 = (q & 1) != 0;
    const bool qb1 = (q & 2) != 0;

    // u accumulators for t=0 (x_0 . Wi quarter-rows)
    int u[4];
    {
        const int4 xx = ((const int4*)xlds)[q];
        #pragma unroll
        for (int i = 0; i < 4; ++i) {
            int s = sdot4i8(xx.x, wiq[i].x, 0);
            s = sdot4i8(xx.y, wiq[i].y, s);
            s = sdot4i8(xx.z, wiq[i].z, s);
            u[i] = sdot4i8(xx.w, wiq[i].w, s);
        }
    }
    // x-quarter for t=1, held in a register across the barrier (distance-2 scheme)
    int4 xc = ((const int4*)xlds)[4 + q];

    // ---- main recurrence: 1024 steps, no global traffic, 1 barrier/step ----
    #pragma unroll 2
    for (int t = 0; t < TSEQ; ++t) {
        // issue LDS reads first: this lane's k-quarter of h_t, and x for t+2
        int4 hh[4];
        {
            const int4* hP = (const int4*)hbuf[t & 1];
            #pragma unroll
            for (int r = 0; r < 4; ++r) hh[r] = hP[q * 4 + r];
        }
        const int4 xnext = ((const int4*)xlds)[(t + 2) * 4 + q]; // pad covers t=1022/1023

        // u for step t+1 from REGISTER xc — no LDS dependency, so these 16
        // sdots issue inside the ds_read-h latency bubble.
        int un[4];
        #pragma unroll
        for (int i = 0; i < 4; ++i) {
            int s = sdot4i8(xc.x, wiq[i].x, 0);
            s = sdot4i8(xc.y, wiq[i].y, s);
            s = sdot4i8(xc.z, wiq[i].z, s);
            un[i] = sdot4i8(xc.w, wiq[i].w, s);
        }

        // z partials: FOUR 4-deep chains per output (shorter chain-through)
        int za[4], zb[4], zc[4], zd[4];
        #pragma unroll
        for (int i = 0; i < 4; ++i) {
            int s0 = u[i];
            s0 = sdot4i8(hh[0].x, wr[i * 4 + 0].x, s0);
            s0 = sdot4i8(hh[0].y, wr[i * 4 + 0].y, s0);
            s0 = sdot4i8(hh[0].z, wr[i * 4 + 0].z, s0);
            s0 = sdot4i8(hh[0].w, wr[i * 4 + 0].w, s0);
            int s1 = 0;
            s1 = sdot4i8(hh[1].x, wr[i * 4 + 1].x, s1);
            s1 = sdot4i8(hh[1].y, wr[i * 4 + 1].y, s1);
            s1 = sdot4i8(hh[1].z, wr[i * 4 + 1].z, s1);
            s1 = sdot4i8(hh[1].w, wr[i * 4 + 1].w, s1);
            int s2 = 0;
            s2 = sdot4i8(hh[2].x, wr[i * 4 + 2].x, s2);
            s2 = sdot4i8(hh[2].y, wr[i * 4 + 2].y, s2);
            s2 = sdot4i8(hh[2].z, wr[i * 4 + 2].z, s2);
            s2 = sdot4i8(hh[2].w, wr[i * 4 + 2].w, s2);
            int s3 = 0;
            s3 = sdot4i8(hh[3].x, wr[i * 4 + 3].x, s3);
            s3 = sdot4i8(hh[3].y, wr[i * 4 + 3].y, s3);
            s3 = sdot4i8(hh[3].z, wr[i * 4 + 3].z, s3);
            s3 = sdot4i8(hh[3].w, wr[i * 4 + 3].w, s3);
            za[i] = s0; zb[i] = s1; zc[i] = s2; zd[i] = s3;
        }

        // quad-reduce all 4 outputs, then lane q keeps output obase+q only
        const int z0 = qsum((za[0] + zb[0]) + (zc[0] + zd[0]));
        const int z1 = qsum((za[1] + zb[1]) + (zc[1] + zd[1]));
        const int z2 = qsum((za[2] + zb[2]) + (zc[2] + zd[2]));
        const int z3 = qsum((za[3] + zb[3]) + (zc[3] + zd[3]));
        const int zlo = qb0 ? z1 : z0;
        const int zhi = qb0 ? z3 : z2;
        const int z   = qb1 ? zhi : zlo;

        // exact modrelu + 8-bit requantize (v3 arithmetic, verbatim)
        const float zf = (float)z;
        const float t1 = fmaf(fabsf(zf), 0.0009765625f, bv);
        const float t2 = fmaxf(t1, 0.0f);
        const float r  = rintf(t2 * 128.0f);
        const int vpos = (int)fminf(r, 127.0f);
        const int vneg = -(int)fminf(r, 128.0f);
        int hv = (z < 0) ? vneg : vpos;
        hv = (z == 0) ? 0 : hv;

        ((signed char*)hbuf[(t + 1) & 1])[tid] = (signed char)hv;

        #pragma unroll
        for (int i = 0; i < 4; ++i) u[i] = un[i];
        xc = xnext;
        __syncthreads();
    }

    // ---- epilogue: out[b, o] = h_last . Wo_row(o) / 1024  (h_1024 in hbuf[0]) ----
    if (tid < ODIM) {
        const int4* wo = (const int4*)wstage;
        const int4* hl = (const int4*)hbuf[0];
        int a0 = 0, a1 = 0, a2 = 0, a3 = 0;
        #pragma unroll
        for (int i = 0; i < 16; ++i) {
            int4 w4 = wo[tid * 16 + i];
            int4 h4 = hl[i];
            a0 = sdot4i8(h4.x, w4.x, a0);
            a1 = sdot4i8(h4.y, w4.y, a1);
            a2 = sdot4i8(h4.z, w4.z, a2);
            a3 = sdot4i8(h4.w, w4.w, a3);
        }
        out[brow * ODIM + tid] = (float)((a0 + a1) + (a2 + a3)) * 0.0009765625f;
    }
}

extern "C" void kernel_launch(void* const* d_in, const int* in_sizes, int n_in,
                              void* d_out, int out_size, void* d_ws, size_t ws_size,
                              hipStream_t stream) {
    const float* x  = (const float*)d_in[0];   // [B, T, I]
    const float* Wi = (const float*)d_in[1];   // [H, I]
    const float* Wr = (const float*)d_in[2];   // [H, H]
    const float* Wo = (const float*)d_in[3];   // [O, H]
    const float* b  = (const float*)d_in[4];   // [H]
    float* out = (float*)d_out;                // [B, O]

    const int B = in_sizes[0] / (TSEQ * IDIM); // 256
    qornn_kernel<<<B, HDIM, 0, stream>>>(x, Wi, Wr, Wo, b, out);
}